// Round 8
// baseline (277.531 us; speedup 1.0000x reference)
//
#include <hip/hip_runtime.h>
#include <hip/hip_bf16.h>
#include <stdint.h>

#define H_ 8
#define NS_ 2048
#define C_ 512
#define HD_ 64
#define SCALE_ 0.125f
#define NEG_ -10000.0f
#define LOG2E_ 1.4426950408889634f
#define MFIX_ 4.0f

typedef _Float16 f16x8_t __attribute__((ext_vector_type(8)));
typedef _Float16 f16x4_t __attribute__((ext_vector_type(4)));
typedef float f32x4_t __attribute__((ext_vector_type(4)));

#define MFMAH(a, b, c) __builtin_amdgcn_mfma_f32_16x16x32_f16(a, b, c, 0, 0, 0)

__device__ inline f16x8_t load_h8(const _Float16* p) {
    return *reinterpret_cast<const f16x8_t*>(p);
}

// async global->LDS, 16B per lane; LDS dest = uniform base + lane*16
__device__ inline void gload_lds16(const void* g, void* l) {
    __builtin_amdgcn_global_load_lds(
        (const __attribute__((address_space(1))) unsigned int*)g,
        (__attribute__((address_space(3))) unsigned int*)l, 16, 0, 0);
}

__device__ inline unsigned orderF(float v) {
    unsigned u = __float_as_uint(v);
    return (u & 0x80000000u) ? ~u : (u | 0x80000000u);
}
__device__ inline unsigned long long packVR(float v, int idx) {
    return ((unsigned long long)orderF(v) << 32) | (unsigned)(~idx);
}
__device__ inline unsigned long long max64(unsigned long long a, unsigned long long b) {
    return a > b ? a : b;
}
__device__ inline unsigned long long shflx64(unsigned long long x, int m) {
    unsigned lo = (unsigned)x, hi = (unsigned)(x >> 32);
    lo = __shfl_xor(lo, m, 64);
    hi = __shfl_xor(hi, m, 64);
    return ((unsigned long long)hi << 32) | lo;
}

// ---------------------------------------------------------------------------
// K0: all four 512x512 weights -> f16 hi/lo splits in one launch.
// ---------------------------------------------------------------------------
__global__ __launch_bounds__(256) void wsplit4(
        const float* __restrict__ w0, const float* __restrict__ w1,
        const float* __restrict__ w2, const float* __restrict__ w3,
        _Float16* __restrict__ hi, _Float16* __restrict__ lo)
{
    const int i = blockIdx.x * 256 + threadIdx.x;            // 65536 float4 / W
    const int y = blockIdx.y;
    const float* src = (y == 0) ? w0 : (y == 1) ? w1 : (y == 2) ? w2 : w3;
    const float4 v = reinterpret_cast<const float4*>(src)[i];
    f16x4_t hv, lv;
    hv[0] = (_Float16)v.x; hv[1] = (_Float16)v.y;
    hv[2] = (_Float16)v.z; hv[3] = (_Float16)v.w;
    lv[0] = (_Float16)(v.x - (float)hv[0]);
    lv[1] = (_Float16)(v.y - (float)hv[1]);
    lv[2] = (_Float16)(v.z - (float)hv[2]);
    lv[3] = (_Float16)(v.w - (float)hv[3]);
    const size_t o = ((size_t)y << 16) + i;                  // float4 index
    reinterpret_cast<f16x4_t*>(hi)[o] = hv;
    reinterpret_cast<f16x4_t*>(lo)[o] = lv;
}

// ---------------------------------------------------------------------------
// K1: projection GEMM (q/k/v via grid.z). 3-term split-f16 MFMA (~fp32).
// z<2: hi/lo split out [bh][n][d]; z==2: V tiled [bh][key>>5][d][k'] with
// k' = ((key&15)<<1)|((key>>4)&1)  (interleaved to match attn_pv's packed P).
// ---------------------------------------------------------------------------
__global__ __launch_bounds__(256) void proj_gemm(
        const float* __restrict__ qin, const float* __restrict__ kin,
        const float* __restrict__ vin,
        const _Float16* __restrict__ wHall, const _Float16* __restrict__ wLall,
        _Float16* __restrict__ qhi, _Float16* __restrict__ qlo,
        _Float16* __restrict__ khi, _Float16* __restrict__ klo,
        _Float16* __restrict__ vT)
{
    __shared__ __attribute__((aligned(16))) _Float16 Wsh[2][2][4096];  // 32 KB
    const int zz = blockIdx.z;
    const float* A32 = (zz == 0) ? qin : (zz == 1) ? kin : vin;
    const _Float16* Wh = wHall + ((size_t)zz << 18);
    const _Float16* Wl = wLall + ((size_t)zz << 18);
    const int t = threadIdx.x, w = t >> 6, lane = t & 63;
    const int m16 = lane & 15, quad = lane >> 4;
    const int bm = blockIdx.x << 7, bn = blockIdx.y << 6;
    const int r0 = bm + (w << 5) + m16, r1 = r0 + 16;
    const int krow = lane >> 3, kblk = (lane & 7) ^ (krow & 7);
    const int e = m16 & 7;
    const int s00 = (quad ^ e) << 3, s01 = ((4 + quad) ^ e) << 3;
    const f32x4_t z = {0.f, 0.f, 0.f, 0.f};
    f32x4_t acc[2][4];
    #pragma unroll
    for (int rs = 0; rs < 2; rs++)
        #pragma unroll
        for (int tl = 0; tl < 4; tl++) acc[rs][tl] = z;

    auto stageW = [&](int buf, int kc) {
        #pragma unroll
        for (int ci = 0; ci < 4; ci++) {
            const int pp = (w << 2) + ci;
            const int s = pp >> 3, pj = pp & 7;
            const _Float16* src = (s ? Wl : Wh)
                + (size_t)(bn + (pj << 3) + krow) * C_ + kc + (kblk << 3);
            gload_lds16(src, &Wsh[buf][s][pj << 9]);
        }
    };
    auto loadA = [&](int kc, f16x8_t* d) {
        #pragma unroll
        for (int rs = 0; rs < 2; rs++) {
            const float* pr = A32 + (size_t)(rs ? r1 : r0) * C_ + kc + (quad << 3);
            #pragma unroll
            for (int seg = 0; seg < 2; seg++) {
                f16x8_t hv, lv;
                #pragma unroll
                for (int i = 0; i < 8; i++) {
                    const float x = pr[seg * 32 + i];
                    const _Float16 hh = (_Float16)x;
                    hv[i] = hh;
                    lv[i] = (_Float16)(x - (float)hh);
                }
                d[rs * 4 + seg] = hv;
                d[rs * 4 + seg + 2] = lv;
            }
        }
    };

    f16x8_t cA[8], nA[8];
    stageW(0, 0);
    loadA(0, cA);
    for (int ch = 0; ch < 8; ch++) {
        __syncthreads();
        if (ch + 1 < 8) {
            stageW((ch + 1) & 1, (ch + 1) << 6);
            loadA((ch + 1) << 6, nA);
        }
        const _Float16* W0 = Wsh[ch & 1][0];
        const _Float16* W1 = Wsh[ch & 1][1];
        #pragma unroll
        for (int tl = 0; tl < 4; tl++) {
            const int j64 = ((tl << 4) + m16) << 6;
            const f16x8_t bh0 = load_h8(&W0[j64 + s00]);
            const f16x8_t bh1 = load_h8(&W0[j64 + s01]);
            const f16x8_t bl0 = load_h8(&W1[j64 + s00]);
            const f16x8_t bl1 = load_h8(&W1[j64 + s01]);
            f32x4_t c0 = acc[0][tl];
            c0 = MFMAH(cA[0], bh0, c0); c0 = MFMAH(cA[1], bh1, c0);
            c0 = MFMAH(cA[2], bh0, c0); c0 = MFMAH(cA[3], bh1, c0);
            c0 = MFMAH(cA[0], bl0, c0); c0 = MFMAH(cA[1], bl1, c0);
            acc[0][tl] = c0;
            f32x4_t c1 = acc[1][tl];
            c1 = MFMAH(cA[4], bh0, c1); c1 = MFMAH(cA[5], bh1, c1);
            c1 = MFMAH(cA[6], bh0, c1); c1 = MFMAH(cA[7], bh1, c1);
            c1 = MFMAH(cA[4], bl0, c1); c1 = MFMAH(cA[5], bl1, c1);
            acc[1][tl] = c1;
        }
        #pragma unroll
        for (int i = 0; i < 8; i++) cA[i] = nA[i];
    }
    const int by = blockIdx.y;
    _Float16* o1 = (zz == 0) ? qhi : khi;
    _Float16* o2 = (zz == 0) ? qlo : klo;
    #pragma unroll
    for (int rs = 0; rs < 2; rs++) {
        #pragma unroll
        for (int tl = 0; tl < 4; tl++) {
            #pragma unroll
            for (int r = 0; r < 4; r++) {
                const int gr = bm + (w << 5) + (rs << 4) + (quad << 2) + r;
                const float val = acc[rs][tl][r];
                const int b = gr >> 11, n = gr & 2047;
                const int d = (tl << 4) + m16;
                const int bh = (b << 3) + by;
                if (zz == 2) {
                    const int kp = ((n & 15) << 1) | ((n >> 4) & 1);
                    vT[(((size_t)((bh << 6) + (n >> 5)) << 6) + d) * 32 + kp] = (_Float16)val;
                } else {
                    const size_t idx = ((((size_t)bh << 11) + n) << 6) + d;
                    const _Float16 hh = (_Float16)val;
                    o1[idx] = hh;
                    o2[idx] = (_Float16)(val - (float)hh);
                }
            }
        }
    }
}

// ---------------------------------------------------------------------------
// K2: MFMA split-f16 argmax, direct-global K loads (no LDS staging, no
// K-loop barriers). 32 rows/wave, 32-key chunks, key-split x4.
// Row argmax -> global atomicMax; col argmax -> in-lane reduce, quad
// butterfly, LDS atomicMax, block merge. XCD-pinned bh pairs.
// ---------------------------------------------------------------------------
__global__ __launch_bounds__(256, 4) void argmax_mfma(
        const _Float16* __restrict__ qhi, const _Float16* __restrict__ qlo,
        const _Float16* __restrict__ khi, const _Float16* __restrict__ klo,
        unsigned long long* __restrict__ rowP, unsigned long long* __restrict__ colP)
{
    __shared__ unsigned long long colbest[512];                        // 4 KB
    const int bx = blockIdx.x;
    const int bh = ((bx & 7) << 1) | (bx >> 9);
    const int mid = (bx >> 3) & 63;
    const int rt = mid & 15, ks = mid >> 4;
    const int t = threadIdx.x, w = t >> 6, lane = t & 63;
    const int m16 = lane & 15, quad = lane >> 4;
    const int wrow = (rt << 7) + (w << 5);
    const size_t qoff = ((((size_t)bh << 11) + wrow + m16) << 6) + (quad << 3);
    const f16x8_t a00h = load_h8(qhi + qoff),        a01h = load_h8(qhi + qoff + 32);
    const f16x8_t a00l = load_h8(qlo + qoff),        a01l = load_h8(qlo + qoff + 32);
    const f16x8_t a10h = load_h8(qhi + qoff + 1024), a11h = load_h8(qhi + qoff + 1056);
    const f16x8_t a10l = load_h8(qlo + qoff + 1024), a11l = load_h8(qlo + qoff + 1056);
    for (int c = t; c < 512; c += 256) colbest[c] = 0;
    __syncthreads();
    const size_t kofs = ((((size_t)bh << 11) + (ks << 9) + m16) << 6) + (quad << 3);
    const _Float16* kph = khi + kofs;
    const _Float16* kpl = klo + kofs;
    float bv0[4] = {-3.4e38f, -3.4e38f, -3.4e38f, -3.4e38f};
    float bv1[4] = {-3.4e38f, -3.4e38f, -3.4e38f, -3.4e38f};
    int bc0[4] = {0, 0, 0, 0}, bc1[4] = {0, 0, 0, 0};
    const f32x4_t z = {0.f, 0.f, 0.f, 0.f};

    for (int ch = 0; ch < 16; ch++) {
        const size_t co = (size_t)ch << 11;
        const f16x8_t b00h = load_h8(kph + co);        const f16x8_t b01h = load_h8(kph + co + 32);
        const f16x8_t b10h = load_h8(kph + co + 1024); const f16x8_t b11h = load_h8(kph + co + 1056);
        const f16x8_t b00l = load_h8(kpl + co);        const f16x8_t b01l = load_h8(kpl + co + 32);
        const f16x8_t b10l = load_h8(kpl + co + 1024); const f16x8_t b11l = load_h8(kpl + co + 1056);
        f32x4_t c0 = MFMAH(a00h, b00h, z);
        c0 = MFMAH(a01h, b01h, c0);
        c0 = MFMAH(a00l, b00h, c0); c0 = MFMAH(a01l, b01h, c0);
        c0 = MFMAH(a00h, b00l, c0); c0 = MFMAH(a01h, b01l, c0);
        f32x4_t c1 = MFMAH(a00h, b10h, z);
        c1 = MFMAH(a01h, b11h, c1);
        c1 = MFMAH(a00l, b10h, c1); c1 = MFMAH(a01l, b11h, c1);
        c1 = MFMAH(a00h, b10l, c1); c1 = MFMAH(a01h, b11l, c1);
        f32x4_t c2 = MFMAH(a10h, b00h, z);
        c2 = MFMAH(a11h, b01h, c2);
        c2 = MFMAH(a10l, b00h, c2); c2 = MFMAH(a11l, b01h, c2);
        c2 = MFMAH(a10h, b00l, c2); c2 = MFMAH(a11h, b01l, c2);
        f32x4_t c3 = MFMAH(a10h, b10h, z);
        c3 = MFMAH(a11h, b11h, c3);
        c3 = MFMAH(a10l, b10h, c3); c3 = MFMAH(a11l, b11h, c3);
        c3 = MFMAH(a10h, b10l, c3); c3 = MFMAH(a11h, b11l, c3);
        const int gc0 = (ks << 9) + (ch << 5) + m16;
        const int gc1 = gc0 + 16;
        #pragma unroll
        for (int r = 0; r < 4; r++) {
            if (c0[r] > bv0[r]) { bv0[r] = c0[r]; bc0[r] = gc0; }
            if (c1[r] > bv0[r]) { bv0[r] = c1[r]; bc0[r] = gc1; }
            if (c2[r] > bv1[r]) { bv1[r] = c2[r]; bc1[r] = gc0; }
            if (c3[r] > bv1[r]) { bv1[r] = c3[r]; bc1[r] = gc1; }
        }
        // col argmax key-tile 0 (c0: rows rowset0, c2: rowset1)
        float v = c0[0]; int ri = (quad << 2);
        if (c0[1] > v) { v = c0[1]; ri = (quad << 2) + 1; }
        if (c0[2] > v) { v = c0[2]; ri = (quad << 2) + 2; }
        if (c0[3] > v) { v = c0[3]; ri = (quad << 2) + 3; }
        if (c2[0] > v) { v = c2[0]; ri = 16 + (quad << 2); }
        if (c2[1] > v) { v = c2[1]; ri = 16 + (quad << 2) + 1; }
        if (c2[2] > v) { v = c2[2]; ri = 16 + (quad << 2) + 2; }
        if (c2[3] > v) { v = c2[3]; ri = 16 + (quad << 2) + 3; }
        unsigned long long pk0 = packVR(v, wrow + ri);
        pk0 = max64(pk0, shflx64(pk0, 16));
        pk0 = max64(pk0, shflx64(pk0, 32));
        // key-tile 1 (c1, c3)
        v = c1[0]; ri = (quad << 2);
        if (c1[1] > v) { v = c1[1]; ri = (quad << 2) + 1; }
        if (c1[2] > v) { v = c1[2]; ri = (quad << 2) + 2; }
        if (c1[3] > v) { v = c1[3]; ri = (quad << 2) + 3; }
        if (c3[0] > v) { v = c3[0]; ri = 16 + (quad << 2); }
        if (c3[1] > v) { v = c3[1]; ri = 16 + (quad << 2) + 1; }
        if (c3[2] > v) { v = c3[2]; ri = 16 + (quad << 2) + 2; }
        if (c3[3] > v) { v = c3[3]; ri = 16 + (quad << 2) + 3; }
        unsigned long long pk1 = packVR(v, wrow + ri);
        pk1 = max64(pk1, shflx64(pk1, 16));
        pk1 = max64(pk1, shflx64(pk1, 32));
        if (quad == 0)      atomicMax(&colbest[(ch << 5) + m16], pk0);
        else if (quad == 1) atomicMax(&colbest[(ch << 5) + 16 + m16], pk1);
    }
    #pragma unroll
    for (int r = 0; r < 4; r++) {
        unsigned long long p0 = packVR(bv0[r], bc0[r]);
        p0 = max64(p0, shflx64(p0, 1)); p0 = max64(p0, shflx64(p0, 2));
        p0 = max64(p0, shflx64(p0, 4)); p0 = max64(p0, shflx64(p0, 8));
        if (m16 == 0)
            atomicMax(rowP + ((size_t)bh << 11) + wrow + (quad << 2) + r, p0);
        unsigned long long p1 = packVR(bv1[r], bc1[r]);
        p1 = max64(p1, shflx64(p1, 1)); p1 = max64(p1, shflx64(p1, 2));
        p1 = max64(p1, shflx64(p1, 4)); p1 = max64(p1, shflx64(p1, 8));
        if (m16 == 0)
            atomicMax(rowP + ((size_t)bh << 11) + wrow + 16 + (quad << 2) + r, p1);
    }
    __syncthreads();
    for (int c = t; c < 512; c += 256)
        atomicMax(colP + ((size_t)bh << 11) + (ks << 9) + c, colbest[c]);
}

// ---------------------------------------------------------------------------
// K3: cycle-consistency resolve -> vn[b,h,j] = valid*NEG*LOG2E - MFIX
// ---------------------------------------------------------------------------
__global__ __launch_bounds__(256) void resolve(const unsigned long long* __restrict__ q2kP,
        const unsigned long long* __restrict__ k2qP, const int* __restrict__ supp_mask,
        const float* __restrict__ supp_valid, float* __restrict__ vn)
{
    const int t = blockIdx.x * 256 + threadIdx.x;      // 32768 = B*H*NS
    const int bh = t >> 11, j = t & 2047, b = bh >> 3;
    const unsigned k2q = 0xFFFFFFFFu - (unsigned)(k2qP[t] & 0xFFFFFFFFull);
    const unsigned rm  = 0xFFFFFFFFu - (unsigned)(q2kP[(bh << 11) + k2q] & 0xFFFFFFFFull);
    const int asso = supp_mask[(b << 11) + j] == supp_mask[(b << 11) + (int)rm];
    const float valid = asso ? supp_valid[(b << 11) + j] : 1.0f;
    vn[t] = fmaf(valid, NEG_ * LOG2E_, -MFIX_);
}

// ---------------------------------------------------------------------------
// K4: fused attention, direct-global K/V loads, ZERO barriers. 32 rows/wave,
// key-split x4 (1024 blocks, 4/CU). p = exp2(s+vn) (fixed max); P packed as
// (p0,p1) u32 into wave-private stride-20 LDS strips (k'-interleaved order,
// matching vT); l via ones-MFMA; partial x (f32) + l per ks.
// ---------------------------------------------------------------------------
__global__ __launch_bounds__(256, 4) void attn_pv(
        const _Float16* __restrict__ qh, const _Float16* __restrict__ kh,
        const _Float16* __restrict__ vT, const float* __restrict__ vnG,
        float* __restrict__ xp, float* __restrict__ lp)
{
    __shared__ __attribute__((aligned(16))) unsigned pbuf[4][2][320];  // 10 KB
    const int bx = blockIdx.x;
    const int bh = ((bx & 7) << 1) | (bx >> 9);
    const int mid = (bx >> 3) & 63;
    const int rt = mid & 15, ks = mid >> 4;
    const int t = threadIdx.x, w = t >> 6, lane = t & 63;
    const int m16 = lane & 15, quad = lane >> 4;
    const int rowbase = (rt << 7) + (w << 5);
    const size_t qoff = ((((size_t)bh << 11) + rowbase + m16) << 6) + (quad << 3);
    const f16x8_t a0 = load_h8(qh + qoff),        a1 = load_h8(qh + qoff + 32);
    const f16x8_t a2 = load_h8(qh + qoff + 1024), a3 = load_h8(qh + qoff + 1056);
    const float KS = SCALE_ * LOG2E_;
    f16x8_t ones;
    #pragma unroll
    for (int i = 0; i < 8; i++) ones[i] = (_Float16)1.0f;
    const f32x4_t z = {0.f, 0.f, 0.f, 0.f};
    f32x4_t xa0[4], xa1[4], la0 = z, la1 = z;
    #pragma unroll
    for (int nt = 0; nt < 4; nt++) { xa0[nt] = z; xa1[nt] = z; }
    const _Float16* kp = kh + ((((size_t)bh << 11) + (ks << 9) + m16) << 6) + (quad << 3);
    const _Float16* vp = vT + (((size_t)((bh << 6) + (ks << 4)) << 6) + m16) * 32 + (quad << 3);
    const float* vnp = vnG + (bh << 11) + (ks << 9);
    unsigned* pw0 = pbuf[w][0];
    unsigned* pw1 = pbuf[w][1];

    for (int ch = 0; ch < 16; ch++) {
        const size_t co = (size_t)ch << 11;
        const f16x8_t b00 = load_h8(kp + co);
        const f16x8_t b01 = load_h8(kp + co + 32);
        const f16x8_t b10 = load_h8(kp + co + 1024);
        const f16x8_t b11 = load_h8(kp + co + 1056);
        f32x4_t c0 = MFMAH(a0, b00, z); c0 = MFMAH(a1, b01, c0);
        f32x4_t c1 = MFMAH(a0, b10, z); c1 = MFMAH(a1, b11, c1);
        f32x4_t c2 = MFMAH(a2, b00, z); c2 = MFMAH(a3, b01, c2);
        f32x4_t c3 = MFMAH(a2, b10, z); c3 = MFMAH(a3, b11, c3);
        const float vn0 = vnp[(ch << 5) + m16], vn1 = vnp[(ch << 5) + 16 + m16];
        #pragma unroll
        for (int r = 0; r < 4; r++) {
            union { _Float16 h[2]; unsigned u; } pk0, pk1;
            pk0.h[0] = (_Float16)exp2f(fmaf(c0[r], KS, vn0));  // key kc+m16    -> k'=2*m16
            pk0.h[1] = (_Float16)exp2f(fmaf(c1[r], KS, vn1));  // key kc+16+m16 -> k'=2*m16+1
            pw0[((quad << 2) + r) * 20 + m16] = pk0.u;
            pk1.h[0] = (_Float16)exp2f(fmaf(c2[r], KS, vn0));
            pk1.h[1] = (_Float16)exp2f(fmaf(c3[r], KS, vn1));
            pw1[((quad << 2) + r) * 20 + m16] = pk1.u;
        }
        __threadfence_block();   // order P writes before same-wave P reads
        const f16x8_t pa0 = *reinterpret_cast<const f16x8_t*>(&pw0[m16 * 20 + (quad << 2)]);
        const f16x8_t pa1 = *reinterpret_cast<const f16x8_t*>(&pw1[m16 * 20 + (quad << 2)]);
        la0 = MFMAH(pa0, ones, la0);
        la1 = MFMAH(pa1, ones, la1);
        #pragma unroll
        for (int nt = 0; nt < 4; nt++) {
            const f16x8_t vb = load_h8(vp + co + (nt << 9));
            xa0[nt] = MFMAH(pa0, vb, xa0[nt]);
            xa1[nt] = MFMAH(pa1, vb, xa1[nt]);
        }
    }
    const int b = bh >> 3, h = bh & 7;
    if (m16 == 0) {
        #pragma unroll
        for (int r = 0; r < 4; r++) {
            lp[((size_t)ks << 15) + (bh << 11) + rowbase + (quad << 2) + r] = la0[r];
            lp[((size_t)ks << 15) + (bh << 11) + rowbase + 16 + (quad << 2) + r] = la1[r];
        }
    }
    const size_t xbase = ((size_t)ks << 21);
    #pragma unroll
    for (int r = 0; r < 4; r++) {
        const int row0 = rowbase + (quad << 2) + r;
        #pragma unroll
        for (int nt = 0; nt < 4; nt++) {
            xp[xbase + (((size_t)(b << 11) + row0) << 9) + (h << 6) + (nt << 4) + m16] = xa0[nt][r];
            xp[xbase + (((size_t)(b << 11) + row0 + 16) << 9) + (h << 6) + (nt << 4) + m16] = xa1[nt][r];
        }
    }
}

// ---------------------------------------------------------------------------
// K5: output GEMM. A = (sum of 4 xp partials) * (1/sum of 4 l partials),
// split to f16 hi/lo on the fly; out[m,j] = sum_k A[m,k]*Wproj[j,k].
// ---------------------------------------------------------------------------
__global__ __launch_bounds__(256) void out_gemm(
        const float* __restrict__ xp, const float* __restrict__ lp,
        const _Float16* __restrict__ Wh, const _Float16* __restrict__ Wl,
        float* __restrict__ outF)
{
    __shared__ __attribute__((aligned(16))) _Float16 Wsh[2][2][4096];  // 32 KB
    const int t = threadIdx.x, w = t >> 6, lane = t & 63;
    const int m16 = lane & 15, quad = lane >> 4;
    const int bm = blockIdx.x << 7, bn = blockIdx.y << 6;
    const int r0 = bm + (w << 5) + m16, r1 = r0 + 16;
    const int krow = lane >> 3, kblk = (lane & 7) ^ (krow & 7);
    const int e = m16 & 7;
    const int s00 = (quad ^ e) << 3, s01 = ((4 + quad) ^ e) << 3;
    const f32x4_t z = {0.f, 0.f, 0.f, 0.f};
    f32x4_t acc[2][4];
    #pragma unroll
    for (int rs = 0; rs < 2; rs++)
        #pragma unroll
        for (int tl = 0; tl < 4; tl++) acc[rs][tl] = z;

    auto stageW = [&](int buf, int kc) {
        #pragma unroll
        for (int ci = 0; ci < 4; ci++) {
            const int pp = (w << 2) + ci;
            const int s = pp >> 3, pj = pp & 7;
            const _Float16* src = (s ? Wl : Wh)
                + (size_t)(bn + (pj << 3) + krow) * C_ + kc + (kblk << 3);
            gload_lds16(src, &Wsh[buf][s][pj << 9]);
        }
    };
    auto loadA = [&](int ch, f16x8_t* d) {
        const int kc = ch << 6;                       // head = ch
        #pragma unroll
        for (int rs = 0; rs < 2; rs++) {
            const int r = rs ? r1 : r0;
            const int b = r >> 11, n = r & 2047;
            const size_t li = ((size_t)((b << 3) + ch) << 11) + n;
            const float linv = 1.0f / (lp[li] + lp[32768 + li] + lp[65536 + li] + lp[98304 + li]);
            const size_t base = ((size_t)r << 9) + kc + (quad << 3);
            #pragma unroll
            for (int seg = 0; seg < 2; seg++) {
                f16x8_t hv, lv;
                #pragma unroll
                for (int i = 0; i < 8; i++) {
                    const size_t o = base + seg * 32 + i;
                    const float x = (xp[o] + xp[2097152 + o] + xp[4194304 + o] + xp[6291456 + o]) * linv;
                    const _Float16 hh = (_Float16)x;
                    hv[i] = hh;
                    lv[i] = (_Float16)(x - (float)hh);
                }
                d[rs * 4 + seg] = hv;
                d[rs * 4 + seg + 2] = lv;
            }
        }
    };

    f16x8_t cA[8], nA[8];
    stageW(0, 0);
    loadA(0, cA);
    for (int ch = 0; ch < 8; ch++) {
        __syncthreads();
        if (ch + 1 < 8) {
            stageW((ch + 1) & 1, (ch + 1) << 6);
            loadA(ch + 1, nA);
        }
        const _Float16* W0 = Wsh[ch & 1][0];
        const _Float16* W1 = Wsh[ch & 1][1];
        #pragma unroll
        for (int tl = 0; tl < 4; tl++) {
            const int j64 = ((tl << 4) + m16) << 6;
            const f16x8_t bh0 = load_h8(&W0[j64 + s00]);
            const f16x8_t bh1 = load_h8(&W0[j64 + s01]);
            const f16x8_t bl0 = load_h8(&W1[j64 + s00]);
            const f16x8_t bl1 = load_h8(&W1[j64 + s01]);
            f32x4_t c0 = acc[0][tl];
            c0 = MFMAH(cA[0], bh0, c0); c0 = MFMAH(cA[1], bh1, c0);
            c0 = MFMAH(cA[2], bh0, c0); c0 = MFMAH(cA[3], bh1, c0);
            c0 = MFMAH(cA[0], bl0, c0); c0 = MFMAH(cA[1], bl1, c0);
            acc[0][tl] = c0;
            f32x4_t c1 = acc[1][tl];
            c1 = MFMAH(cA[4], bh0, c1); c1 = MFMAH(cA[5], bh1, c1);
            c1 = MFMAH(cA[6], bh0, c1); c1 = MFMAH(cA[7], bh1, c1);
            c1 = MFMAH(cA[4], bl0, c1); c1 = MFMAH(cA[5], bl1, c1);
            acc[1][tl] = c1;
        }
        #pragma unroll
        for (int i = 0; i < 8; i++) cA[i] = nA[i];
    }
    #pragma unroll
    for (int rs = 0; rs < 2; rs++) {
        #pragma unroll
        for (int tl = 0; tl < 4; tl++) {
            #pragma unroll
            for (int r = 0; r < 4; r++) {
                const int gr = bm + (w << 5) + (rs << 4) + (quad << 2) + r;
                const int gj = bn + (tl << 4) + m16;
                outF[(size_t)gr * C_ + gj] = acc[rs][tl][r];
            }
        }
    }
}

// ---------------------------------------------------------------------------
extern "C" void kernel_launch(void* const* d_in, const int* in_sizes, int n_in,
                              void* d_out, int out_size, void* d_ws, size_t ws_size,
                              hipStream_t stream) {
    const float* q  = (const float*)d_in[0];
    const float* k  = (const float*)d_in[1];
    const float* v  = (const float*)d_in[2];
    const float* supp_valid = (const float*)d_in[3];
    const int*   supp_mask  = (const int*)d_in[4];
    const float* Wq = (const float*)d_in[5];
    const float* Wk = (const float*)d_in[6];
    const float* Wv = (const float*)d_in[7];
    const float* Wp = (const float*)d_in[8];
    float* out = (float*)d_out;

    char* p = (char*)d_ws;
    _Float16* qhi = (_Float16*)p;      p += 4194304;   // [bh][n][d]
    _Float16* khi = (_Float16*)p;      p += 4194304;
    _Float16* vT  = (_Float16*)p;      p += 4194304;   // [bh] chunk-tiled (k')
    float* xp     = (float*)p;                         // [4][4096][512] f32 (32MB)
    _Float16* qlo = (_Float16*)p;      p += 4194304;   // aliased under xp (dead
    _Float16* klo = (_Float16*)p;      p += 4194304;   //  after argmax)
    p += 25165824;                                     // rest of xp
    _Float16* wH  = (_Float16*)p;      p += 2097152;   // [4][512*512]
    _Float16* wL  = (_Float16*)p;      p += 2097152;
    unsigned long long* q2kP = (unsigned long long*)p; p += 262144;
    unsigned long long* k2qP = (unsigned long long*)p; p += 262144;
    float* lp = (float*)p;             p += 524288;    // [4][16][2048]
    float* validNeg = (float*)p;       p += 131072;

    hipMemsetAsync(q2kP, 0, 524288, stream);           // rowP + colP zero init

    dim3 bG(256);
    wsplit4<<<dim3(256, 4), bG, 0, stream>>>(Wq, Wk, Wv, Wp, wH, wL);
    proj_gemm<<<dim3(32, 8, 3), bG, 0, stream>>>(q, k, v, wH, wL,
                                                 qhi, qlo, khi, klo, vT);

    argmax_mfma<<<1024, bG, 0, stream>>>(qhi, qlo, khi, klo, q2kP, k2qP);

    resolve<<<128, bG, 0, stream>>>(q2kP, k2qP, supp_mask, supp_valid, validNeg);

    attn_pv<<<1024, bG, 0, stream>>>(qhi, khi, vT, validNeg, xp, lp);

    out_gemm<<<dim3(32, 8), bG, 0, stream>>>(xp, lp,
                                             wH + 3 * 262144, wL + 3 * 262144, out);
}

// Round 9
// 224.566 us; speedup vs baseline: 1.2359x; 1.2359x over previous
//
#include <hip/hip_runtime.h>
#include <hip/hip_bf16.h>
#include <stdint.h>

#define H_ 8
#define NS_ 2048
#define C_ 512
#define HD_ 64
#define SCALE_ 0.125f
#define NEG_ -10000.0f
#define LOG2E_ 1.4426950408889634f
#define MFIX_ 4.0f

typedef _Float16 f16x8_t __attribute__((ext_vector_type(8)));
typedef _Float16 f16x4_t __attribute__((ext_vector_type(4)));
typedef float f32x4_t __attribute__((ext_vector_type(4)));

#define MFMAH(a, b, c) __builtin_amdgcn_mfma_f32_16x16x32_f16(a, b, c, 0, 0, 0)

__device__ inline f16x8_t load_h8(const _Float16* p) {
    return *reinterpret_cast<const f16x8_t*>(p);
}

// async global->LDS, 16B per lane; LDS dest = uniform base + lane*16
__device__ inline void gload_lds16(const void* g, void* l) {
    __builtin_amdgcn_global_load_lds(
        (const __attribute__((address_space(1))) unsigned int*)g,
        (__attribute__((address_space(3))) unsigned int*)l, 16, 0, 0);
}

__device__ inline unsigned orderF(float v) {
    unsigned u = __float_as_uint(v);
    return (u & 0x80000000u) ? ~u : (u | 0x80000000u);
}
__device__ inline unsigned long long packVR(float v, int idx) {
    return ((unsigned long long)orderF(v) << 32) | (unsigned)(~idx);
}
__device__ inline unsigned long long max64(unsigned long long a, unsigned long long b) {
    return a > b ? a : b;
}
__device__ inline unsigned long long shflx64(unsigned long long x, int m) {
    unsigned lo = (unsigned)x, hi = (unsigned)(x >> 32);
    lo = __shfl_xor(lo, m, 64);
    hi = __shfl_xor(hi, m, 64);
    return ((unsigned long long)hi << 32) | lo;
}

// ---------------------------------------------------------------------------
// K0: all four 512x512 weights -> f16 hi/lo splits in one launch.
// ---------------------------------------------------------------------------
__global__ __launch_bounds__(256) void wsplit4(
        const float* __restrict__ w0, const float* __restrict__ w1,
        const float* __restrict__ w2, const float* __restrict__ w3,
        _Float16* __restrict__ hi, _Float16* __restrict__ lo)
{
    const int i = blockIdx.x * 256 + threadIdx.x;            // 65536 float4 / W
    const int y = blockIdx.y;
    const float* src = (y == 0) ? w0 : (y == 1) ? w1 : (y == 2) ? w2 : w3;
    const float4 v = reinterpret_cast<const float4*>(src)[i];
    f16x4_t hv, lv;
    hv[0] = (_Float16)v.x; hv[1] = (_Float16)v.y;
    hv[2] = (_Float16)v.z; hv[3] = (_Float16)v.w;
    lv[0] = (_Float16)(v.x - (float)hv[0]);
    lv[1] = (_Float16)(v.y - (float)hv[1]);
    lv[2] = (_Float16)(v.z - (float)hv[2]);
    lv[3] = (_Float16)(v.w - (float)hv[3]);
    const size_t o = ((size_t)y << 16) + i;                  // float4 index
    reinterpret_cast<f16x4_t*>(hi)[o] = hv;
    reinterpret_cast<f16x4_t*>(lo)[o] = lv;
}

// ---------------------------------------------------------------------------
// K1: projection GEMM (q/k/v via grid.z). 3-term split-f16 MFMA (~fp32).
// Prologue (z==0 blocks) zero-inits the argmax rowP/colP buffers (contiguous
// 512 KB) -- replaces a separate memset dispatch.
// z<2: hi/lo split out [bh][n][d]; z==2: V tiled [bh][key>>5][d][k'] with
// k' = ((key&15)<<1)|((key>>4)&1)  (interleaved to match attn_pv's packed P).
// ---------------------------------------------------------------------------
__global__ __launch_bounds__(256) void proj_gemm(
        const float* __restrict__ qin, const float* __restrict__ kin,
        const float* __restrict__ vin,
        const _Float16* __restrict__ wHall, const _Float16* __restrict__ wLall,
        _Float16* __restrict__ qhi, _Float16* __restrict__ qlo,
        _Float16* __restrict__ khi, _Float16* __restrict__ klo,
        _Float16* __restrict__ vT, unsigned long long* __restrict__ pinit)
{
    __shared__ __attribute__((aligned(16))) _Float16 Wsh[2][2][4096];  // 32 KB
    const int zz = blockIdx.z;
    if (zz == 0) {   // zero rowP+colP (65536 u64 over 256 blocks)
        const int bid = (blockIdx.x << 3) + blockIdx.y;
        pinit[(bid << 8) + threadIdx.x] = 0ull;
    }
    const float* A32 = (zz == 0) ? qin : (zz == 1) ? kin : vin;
    const _Float16* Wh = wHall + ((size_t)zz << 18);
    const _Float16* Wl = wLall + ((size_t)zz << 18);
    const int t = threadIdx.x, w = t >> 6, lane = t & 63;
    const int m16 = lane & 15, quad = lane >> 4;
    const int bm = blockIdx.x << 7, bn = blockIdx.y << 6;
    const int r0 = bm + (w << 5) + m16, r1 = r0 + 16;
    const int krow = lane >> 3, kblk = (lane & 7) ^ (krow & 7);
    const int e = m16 & 7;
    const int s00 = (quad ^ e) << 3, s01 = ((4 + quad) ^ e) << 3;
    const f32x4_t z = {0.f, 0.f, 0.f, 0.f};
    f32x4_t acc[2][4];
    #pragma unroll
    for (int rs = 0; rs < 2; rs++)
        #pragma unroll
        for (int tl = 0; tl < 4; tl++) acc[rs][tl] = z;

    auto stageW = [&](int buf, int kc) {
        #pragma unroll
        for (int ci = 0; ci < 4; ci++) {
            const int pp = (w << 2) + ci;
            const int s = pp >> 3, pj = pp & 7;
            const _Float16* src = (s ? Wl : Wh)
                + (size_t)(bn + (pj << 3) + krow) * C_ + kc + (kblk << 3);
            gload_lds16(src, &Wsh[buf][s][pj << 9]);
        }
    };
    auto loadA = [&](int kc, f16x8_t* d) {
        #pragma unroll
        for (int rs = 0; rs < 2; rs++) {
            const float* pr = A32 + (size_t)(rs ? r1 : r0) * C_ + kc + (quad << 3);
            #pragma unroll
            for (int seg = 0; seg < 2; seg++) {
                f16x8_t hv, lv;
                #pragma unroll
                for (int i = 0; i < 8; i++) {
                    const float x = pr[seg * 32 + i];
                    const _Float16 hh = (_Float16)x;
                    hv[i] = hh;
                    lv[i] = (_Float16)(x - (float)hh);
                }
                d[rs * 4 + seg] = hv;
                d[rs * 4 + seg + 2] = lv;
            }
        }
    };

    f16x8_t cA[8], nA[8];
    stageW(0, 0);
    loadA(0, cA);
    for (int ch = 0; ch < 8; ch++) {
        __syncthreads();
        if (ch + 1 < 8) {
            stageW((ch + 1) & 1, (ch + 1) << 6);
            loadA((ch + 1) << 6, nA);
        }
        const _Float16* W0 = Wsh[ch & 1][0];
        const _Float16* W1 = Wsh[ch & 1][1];
        #pragma unroll
        for (int tl = 0; tl < 4; tl++) {
            const int j64 = ((tl << 4) + m16) << 6;
            const f16x8_t bh0 = load_h8(&W0[j64 + s00]);
            const f16x8_t bh1 = load_h8(&W0[j64 + s01]);
            const f16x8_t bl0 = load_h8(&W1[j64 + s00]);
            const f16x8_t bl1 = load_h8(&W1[j64 + s01]);
            f32x4_t c0 = acc[0][tl];
            c0 = MFMAH(cA[0], bh0, c0); c0 = MFMAH(cA[1], bh1, c0);
            c0 = MFMAH(cA[2], bh0, c0); c0 = MFMAH(cA[3], bh1, c0);
            c0 = MFMAH(cA[0], bl0, c0); c0 = MFMAH(cA[1], bl1, c0);
            acc[0][tl] = c0;
            f32x4_t c1 = acc[1][tl];
            c1 = MFMAH(cA[4], bh0, c1); c1 = MFMAH(cA[5], bh1, c1);
            c1 = MFMAH(cA[6], bh0, c1); c1 = MFMAH(cA[7], bh1, c1);
            c1 = MFMAH(cA[4], bl0, c1); c1 = MFMAH(cA[5], bl1, c1);
            acc[1][tl] = c1;
        }
        #pragma unroll
        for (int i = 0; i < 8; i++) cA[i] = nA[i];
    }
    const int by = blockIdx.y;
    _Float16* o1 = (zz == 0) ? qhi : khi;
    _Float16* o2 = (zz == 0) ? qlo : klo;
    #pragma unroll
    for (int rs = 0; rs < 2; rs++) {
        #pragma unroll
        for (int tl = 0; tl < 4; tl++) {
            #pragma unroll
            for (int r = 0; r < 4; r++) {
                const int gr = bm + (w << 5) + (rs << 4) + (quad << 2) + r;
                const float val = acc[rs][tl][r];
                const int b = gr >> 11, n = gr & 2047;
                const int d = (tl << 4) + m16;
                const int bh = (b << 3) + by;
                if (zz == 2) {
                    const int kp = ((n & 15) << 1) | ((n >> 4) & 1);
                    vT[(((size_t)((bh << 6) + (n >> 5)) << 6) + d) * 32 + kp] = (_Float16)val;
                } else {
                    const size_t idx = ((((size_t)bh << 11) + n) << 6) + d;
                    const _Float16 hh = (_Float16)val;
                    o1[idx] = hh;
                    o2[idx] = (_Float16)(val - (float)hh);
                }
            }
        }
    }
}

// ---------------------------------------------------------------------------
// K2: MFMA split-f16 argmax. 32 rows/wave, 64-key chunks, dbuf LDS staging,
// key-space split x4 (4 blocks/CU). Row argmax -> global atomicMax; col
// argmax -> in-lane reduce, quad butterfly, LDS atomicMax, block merge.
// XCD-pinned: bh pair {2x,2x+1} on XCD x.  [R7 version — B-frags from LDS]
// ---------------------------------------------------------------------------
__global__ __launch_bounds__(256) void argmax_mfma(
        const _Float16* __restrict__ qhi, const _Float16* __restrict__ qlo,
        const _Float16* __restrict__ khi, const _Float16* __restrict__ klo,
        unsigned long long* __restrict__ rowP, unsigned long long* __restrict__ colP)
{
    __shared__ __attribute__((aligned(16))) _Float16 Ksh[2][2][4096];  // 32 KB
    __shared__ unsigned long long colbest[512];                        // 4 KB
    const int bx = blockIdx.x;
    const int bh = ((bx & 7) << 1) | (bx >> 9);
    const int mid = (bx >> 3) & 63;
    const int rt = mid & 15, ks = mid >> 4;
    const int t = threadIdx.x, w = t >> 6, lane = t & 63;
    const int m16 = lane & 15, quad = lane >> 4;
    const int wrow = (rt << 7) + (w << 5);
    const size_t qoff0 = ((((size_t)bh << 11) + wrow + m16) << 6) + (quad << 3);
    const size_t qoff1 = qoff0 + 1024;
    const f16x8_t a00h = load_h8(qhi + qoff0), a01h = load_h8(qhi + qoff0 + 32);
    const f16x8_t a00l = load_h8(qlo + qoff0), a01l = load_h8(qlo + qoff0 + 32);
    const f16x8_t a10h = load_h8(qhi + qoff1), a11h = load_h8(qhi + qoff1 + 32);
    const f16x8_t a10l = load_h8(qlo + qoff1), a11l = load_h8(qlo + qoff1 + 32);
    for (int c = t; c < 512; c += 256) colbest[c] = 0;
    const int krow = lane >> 3, kblk = (lane & 7) ^ (krow & 7);
    const int e = m16 & 7;
    const int s00 = (quad ^ e) << 3, s01 = ((4 + quad) ^ e) << 3;
    const size_t kbase = (((size_t)bh << 11) + (ks << 9)) << 6;
    float bv0[4] = {-3.4e38f, -3.4e38f, -3.4e38f, -3.4e38f};
    float bv1[4] = {-3.4e38f, -3.4e38f, -3.4e38f, -3.4e38f};
    int bc0[4] = {0, 0, 0, 0}, bc1[4] = {0, 0, 0, 0};
    const f32x4_t z = {0.f, 0.f, 0.f, 0.f};

    auto stage = [&](int buf, int cidx) {
        const size_t ce = kbase + ((size_t)cidx << 12);
        #pragma unroll
        for (int ci = 0; ci < 4; ci++) {
            const int pp = (w << 2) + ci;
            const int s = pp >> 3, pj = pp & 7;
            const _Float16* src = (s ? klo : khi) + ce + (((pj << 3) + krow) << 6) + (kblk << 3);
            gload_lds16(src, &Ksh[buf][s][pj << 9]);
        }
    };

    stage(0, 0);
    for (int ch = 0; ch < 8; ch++) {
        __syncthreads();
        if (ch + 1 < 8) stage((ch + 1) & 1, ch + 1);
        const _Float16* K0 = Ksh[ch & 1][0];
        const _Float16* K1 = Ksh[ch & 1][1];
        const int kc0 = (ks << 9) + (ch << 6);
        #pragma unroll
        for (int tl = 0; tl < 4; tl++) {
            const int j64 = ((tl << 4) + m16) << 6;
            const f16x8_t bh0 = load_h8(&K0[j64 + s00]);
            const f16x8_t bh1 = load_h8(&K0[j64 + s01]);
            const f16x8_t bl0 = load_h8(&K1[j64 + s00]);
            const f16x8_t bl1 = load_h8(&K1[j64 + s01]);
            f32x4_t c0 = MFMAH(a00h, bh0, z);
            c0 = MFMAH(a01h, bh1, c0);
            c0 = MFMAH(a00l, bh0, c0); c0 = MFMAH(a01l, bh1, c0);
            c0 = MFMAH(a00h, bl0, c0); c0 = MFMAH(a01h, bl1, c0);
            f32x4_t c1 = MFMAH(a10h, bh0, z);
            c1 = MFMAH(a11h, bh1, c1);
            c1 = MFMAH(a10l, bh0, c1); c1 = MFMAH(a11l, bh1, c1);
            c1 = MFMAH(a10h, bl0, c1); c1 = MFMAH(a11h, bl1, c1);
            const int gc = kc0 + (tl << 4) + m16;
            #pragma unroll
            for (int r = 0; r < 4; r++) {
                if (c0[r] > bv0[r]) { bv0[r] = c0[r]; bc0[r] = gc; }
                if (c1[r] > bv1[r]) { bv1[r] = c1[r]; bc1[r] = gc; }
            }
            // col argmax: in-lane over 8 rows (rowset0 first -> smallest row)
            float v = c0[0]; int ri = (quad << 2);
            if (c0[1] > v) { v = c0[1]; ri = (quad << 2) + 1; }
            if (c0[2] > v) { v = c0[2]; ri = (quad << 2) + 2; }
            if (c0[3] > v) { v = c0[3]; ri = (quad << 2) + 3; }
            if (c1[0] > v) { v = c1[0]; ri = 16 + (quad << 2); }
            if (c1[1] > v) { v = c1[1]; ri = 16 + (quad << 2) + 1; }
            if (c1[2] > v) { v = c1[2]; ri = 16 + (quad << 2) + 2; }
            if (c1[3] > v) { v = c1[3]; ri = 16 + (quad << 2) + 3; }
            unsigned long long pk = packVR(v, wrow + ri);
            pk = max64(pk, shflx64(pk, 16));
            pk = max64(pk, shflx64(pk, 32));
            if (quad == 0) atomicMax(&colbest[(ch << 6) + (tl << 4) + m16], pk);
        }
    }
    #pragma unroll
    for (int r = 0; r < 4; r++) {
        unsigned long long p0 = packVR(bv0[r], bc0[r]);
        p0 = max64(p0, shflx64(p0, 1)); p0 = max64(p0, shflx64(p0, 2));
        p0 = max64(p0, shflx64(p0, 4)); p0 = max64(p0, shflx64(p0, 8));
        if (m16 == 0)
            atomicMax(rowP + ((size_t)bh << 11) + wrow + (quad << 2) + r, p0);
        unsigned long long p1 = packVR(bv1[r], bc1[r]);
        p1 = max64(p1, shflx64(p1, 1)); p1 = max64(p1, shflx64(p1, 2));
        p1 = max64(p1, shflx64(p1, 4)); p1 = max64(p1, shflx64(p1, 8));
        if (m16 == 0)
            atomicMax(rowP + ((size_t)bh << 11) + wrow + 16 + (quad << 2) + r, p1);
    }
    __syncthreads();
    for (int c = t; c < 512; c += 256)
        atomicMax(colP + ((size_t)bh << 11) + (ks << 9) + c, colbest[c]);
}

// ---------------------------------------------------------------------------
// K4: fused attention (resolve folded into prologue). 32 rows/wave, LDS-
// staged K/V (dbuf, XOR swizzle), key-split x4 (1024 blocks, 4/CU).
// p = exp2(s+vn) (fixed max); P packed (p0,p1) u32 -> stride-20 wave strips
// (k'-interleaved, matching vT); l via ones-MFMA; partial x/l per ks.
// ---------------------------------------------------------------------------
__global__ __launch_bounds__(256, 4) void attn_pv(
        const _Float16* __restrict__ qh, const _Float16* __restrict__ kh,
        const _Float16* __restrict__ vT,
        const unsigned long long* __restrict__ q2kP,
        const unsigned long long* __restrict__ k2qP,
        const int* __restrict__ supp_mask, const float* __restrict__ supp_valid,
        float* __restrict__ xp, float* __restrict__ lp)
{
    __shared__ __attribute__((aligned(16))) _Float16 Ksh[2][2048];    // 8 KB
    __shared__ __attribute__((aligned(16))) _Float16 Vsh[2][2048];    // 8 KB
    __shared__ float vnL[512];                                        // 2 KB
    __shared__ __attribute__((aligned(16))) unsigned pbuf[4][2][320]; // 10 KB
    const int bx = blockIdx.x;
    const int bh = ((bx & 7) << 1) | (bx >> 9);
    const int mid = (bx >> 3) & 63;
    const int rt = mid & 15, ks = mid >> 4;
    const int t = threadIdx.x, w = t >> 6, lane = t & 63;
    const int m16 = lane & 15, quad = lane >> 4;
    const int b = bh >> 3, h = bh & 7;
    // --- fused resolve for this block's 512-key slice ---
    for (int c = t; c < 512; c += 256) {
        const int j = (ks << 9) + c;
        const unsigned k2q = ~(unsigned)(k2qP[(bh << 11) + j] & 0xFFFFFFFFull);
        const unsigned rm  = ~(unsigned)(q2kP[(bh << 11) + k2q] & 0xFFFFFFFFull);
        const int asso = supp_mask[(b << 11) + j] == supp_mask[(b << 11) + (int)rm];
        const float valid = asso ? supp_valid[(b << 11) + j] : 1.0f;
        vnL[c] = fmaf(valid, NEG_ * LOG2E_, -MFIX_);
    }
    const int rowbase = (rt << 7) + (w << 5);
    const size_t qoff = ((((size_t)bh << 11) + rowbase + m16) << 6) + (quad << 3);
    const f16x8_t a0 = load_h8(qh + qoff),        a1 = load_h8(qh + qoff + 32);
    const f16x8_t a2 = load_h8(qh + qoff + 1024), a3 = load_h8(qh + qoff + 1056);
    const float KS = SCALE_ * LOG2E_;
    const int krow = lane >> 3, kblk = (lane & 7) ^ ((lane >> 3) & 7);
    const int vrow = lane >> 2, vblk = (lane & 3) ^ ((lane >> 3) & 3);
    const int e = m16 & 7;
    const int s00 = (quad ^ e) << 3, s01 = ((4 + quad) ^ e) << 3;
    const int vsw = (m16 >> 1) & 3;
    f16x8_t ones;
    #pragma unroll
    for (int i = 0; i < 8; i++) ones[i] = (_Float16)1.0f;
    const f32x4_t z = {0.f, 0.f, 0.f, 0.f};
    f32x4_t xa0[4], xa1[4], la0 = z, la1 = z;
    #pragma unroll
    for (int nt = 0; nt < 4; nt++) { xa0[nt] = z; xa1[nt] = z; }
    const size_t kbel = ((size_t)bh << 11) * HD_;
    unsigned* pw0 = pbuf[w][0];
    unsigned* pw1 = pbuf[w][1];

    auto stage = [&](int buf, int ch) {
        const int kcg = (ks << 9) + (ch << 5);
        const size_t ce = kbel + (size_t)kcg * HD_;
        const size_t ve = ((size_t)(bh << 6) + (kcg >> 5)) << 11;
        #pragma unroll
        for (int ci = 0; ci < 2; ci++) {
            const int call = (w << 1) + ci;
            if (call < 4) {
                const _Float16* src = kh + ce + ((call * 8 + krow) << 6) + (kblk << 3);
                gload_lds16(src, &Ksh[buf][call << 9]);
            } else {
                const int j = call - 4;
                const _Float16* src = vT + ve + ((j * 16 + vrow) << 5) + (vblk << 3);
                gload_lds16(src, &Vsh[buf][j << 9]);
            }
        }
    };

    stage(0, 0);
    for (int ch = 0; ch < 16; ch++) {
        __syncthreads();
        if (ch + 1 < 16) stage((ch + 1) & 1, ch + 1);
        const _Float16* K = Ksh[ch & 1];
        const _Float16* V = Vsh[ch & 1];
        const f16x8_t b00 = load_h8(&K[(m16 << 6) + s00]);
        const f16x8_t b01 = load_h8(&K[(m16 << 6) + s01]);
        const f16x8_t b10 = load_h8(&K[((16 + m16) << 6) + s00]);
        const f16x8_t b11 = load_h8(&K[((16 + m16) << 6) + s01]);
        f32x4_t c0 = MFMAH(a0, b00, z); c0 = MFMAH(a1, b01, c0);
        f32x4_t c1 = MFMAH(a0, b10, z); c1 = MFMAH(a1, b11, c1);
        f32x4_t c2 = MFMAH(a2, b00, z); c2 = MFMAH(a3, b01, c2);
        f32x4_t c3 = MFMAH(a2, b10, z); c3 = MFMAH(a3, b11, c3);
        const float vn0 = vnL[(ch << 5) + m16], vn1 = vnL[(ch << 5) + 16 + m16];
        #pragma unroll
        for (int r = 0; r < 4; r++) {
            union { _Float16 hh[2]; unsigned u; } pk0, pk1;
            pk0.hh[0] = (_Float16)exp2f(fmaf(c0[r], KS, vn0));  // key kc+m16    -> k'=2*m16
            pk0.hh[1] = (_Float16)exp2f(fmaf(c1[r], KS, vn1));  // key kc+16+m16 -> k'=2*m16+1
            pw0[((quad << 2) + r) * 20 + m16] = pk0.u;
            pk1.hh[0] = (_Float16)exp2f(fmaf(c2[r], KS, vn0));
            pk1.hh[1] = (_Float16)exp2f(fmaf(c3[r], KS, vn1));
            pw1[((quad << 2) + r) * 20 + m16] = pk1.u;
        }
        __threadfence_block();   // order P writes before same-wave P reads
        const f16x8_t pa0 = *reinterpret_cast<const f16x8_t*>(&pw0[m16 * 20 + (quad << 2)]);
        const f16x8_t pa1 = *reinterpret_cast<const f16x8_t*>(&pw1[m16 * 20 + (quad << 2)]);
        la0 = MFMAH(pa0, ones, la0);
        la1 = MFMAH(pa1, ones, la1);
        #pragma unroll
        for (int nt = 0; nt < 4; nt++) {
            const f16x8_t vb = load_h8(&V[((nt * 16 + m16) << 5) + ((quad ^ vsw) << 3)]);
            xa0[nt] = MFMAH(pa0, vb, xa0[nt]);
            xa1[nt] = MFMAH(pa1, vb, xa1[nt]);
        }
    }
    if (m16 == 0) {
        #pragma unroll
        for (int r = 0; r < 4; r++) {
            lp[((size_t)ks << 15) + (bh << 11) + rowbase + (quad << 2) + r] = la0[r];
            lp[((size_t)ks << 15) + (bh << 11) + rowbase + 16 + (quad << 2) + r] = la1[r];
        }
    }
    const size_t xbase = ((size_t)ks << 21);
    #pragma unroll
    for (int r = 0; r < 4; r++) {
        const int row0 = rowbase + (quad << 2) + r;
        #pragma unroll
        for (int nt = 0; nt < 4; nt++) {
            xp[xbase + (((size_t)(b << 11) + row0) << 9) + (h << 6) + (nt << 4) + m16] = xa0[nt][r];
            xp[xbase + (((size_t)(b << 11) + row0 + 16) << 9) + (h << 6) + (nt << 4) + m16] = xa1[nt][r];
        }
    }
}

// ---------------------------------------------------------------------------
// K5: output GEMM. A = (sum of 4 xp partials) * (1/sum of 4 l partials),
// split to f16 hi/lo on the fly; out[m,j] = sum_k A[m,k]*Wproj[j,k].
// ---------------------------------------------------------------------------
__global__ __launch_bounds__(256) void out_gemm(
        const float* __restrict__ xp, const float* __restrict__ lp,
        const _Float16* __restrict__ Wh, const _Float16* __restrict__ Wl,
        float* __restrict__ outF)
{
    __shared__ __attribute__((aligned(16))) _Float16 Wsh[2][2][4096];  // 32 KB
    const int t = threadIdx.x, w = t >> 6, lane = t & 63;
    const int m16 = lane & 15, quad = lane >> 4;
    const int bm = blockIdx.x << 7, bn = blockIdx.y << 6;
    const int r0 = bm + (w << 5) + m16, r1 = r0 + 16;
    const int krow = lane >> 3, kblk = (lane & 7) ^ (krow & 7);
    const int e = m16 & 7;
    const int s00 = (quad ^ e) << 3, s01 = ((4 + quad) ^ e) << 3;
    const f32x4_t z = {0.f, 0.f, 0.f, 0.f};
    f32x4_t acc[2][4];
    #pragma unroll
    for (int rs = 0; rs < 2; rs++)
        #pragma unroll
        for (int tl = 0; tl < 4; tl++) acc[rs][tl] = z;

    auto stageW = [&](int buf, int kc) {
        #pragma unroll
        for (int ci = 0; ci < 4; ci++) {
            const int pp = (w << 2) + ci;
            const int s = pp >> 3, pj = pp & 7;
            const _Float16* src = (s ? Wl : Wh)
                + (size_t)(bn + (pj << 3) + krow) * C_ + kc + (kblk << 3);
            gload_lds16(src, &Wsh[buf][s][pj << 9]);
        }
    };
    auto loadA = [&](int ch, f16x8_t* d) {
        const int kc = ch << 6;                       // head = ch
        #pragma unroll
        for (int rs = 0; rs < 2; rs++) {
            const int r = rs ? r1 : r0;
            const int b = r >> 11, n = r & 2047;
            const size_t li = ((size_t)((b << 3) + ch) << 11) + n;
            const float linv = 1.0f / (lp[li] + lp[32768 + li] + lp[65536 + li] + lp[98304 + li]);
            const size_t base = ((size_t)r << 9) + kc + (quad << 3);
            #pragma unroll
            for (int seg = 0; seg < 2; seg++) {
                f16x8_t hv, lv;
                #pragma unroll
                for (int i = 0; i < 8; i++) {
                    const size_t o = base + seg * 32 + i;
                    const float x = (xp[o] + xp[2097152 + o] + xp[4194304 + o] + xp[6291456 + o]) * linv;
                    const _Float16 hh = (_Float16)x;
                    hv[i] = hh;
                    lv[i] = (_Float16)(x - (float)hh);
                }
                d[rs * 4 + seg] = hv;
                d[rs * 4 + seg + 2] = lv;
            }
        }
    };

    f16x8_t cA[8], nA[8];
    stageW(0, 0);
    loadA(0, cA);
    for (int ch = 0; ch < 8; ch++) {
        __syncthreads();
        if (ch + 1 < 8) {
            stageW((ch + 1) & 1, (ch + 1) << 6);
            loadA(ch + 1, nA);
        }
        const _Float16* W0 = Wsh[ch & 1][0];
        const _Float16* W1 = Wsh[ch & 1][1];
        #pragma unroll
        for (int tl = 0; tl < 4; tl++) {
            const int j64 = ((tl << 4) + m16) << 6;
            const f16x8_t bh0 = load_h8(&W0[j64 + s00]);
            const f16x8_t bh1 = load_h8(&W0[j64 + s01]);
            const f16x8_t bl0 = load_h8(&W1[j64 + s00]);
            const f16x8_t bl1 = load_h8(&W1[j64 + s01]);
            f32x4_t c0 = acc[0][tl];
            c0 = MFMAH(cA[0], bh0, c0); c0 = MFMAH(cA[1], bh1, c0);
            c0 = MFMAH(cA[2], bh0, c0); c0 = MFMAH(cA[3], bh1, c0);
            c0 = MFMAH(cA[0], bl0, c0); c0 = MFMAH(cA[1], bl1, c0);
            acc[0][tl] = c0;
            f32x4_t c1 = acc[1][tl];
            c1 = MFMAH(cA[4], bh0, c1); c1 = MFMAH(cA[5], bh1, c1);
            c1 = MFMAH(cA[6], bh0, c1); c1 = MFMAH(cA[7], bh1, c1);
            c1 = MFMAH(cA[4], bl0, c1); c1 = MFMAH(cA[5], bl1, c1);
            acc[1][tl] = c1;
        }
        #pragma unroll
        for (int i = 0; i < 8; i++) cA[i] = nA[i];
    }
    #pragma unroll
    for (int rs = 0; rs < 2; rs++) {
        #pragma unroll
        for (int tl = 0; tl < 4; tl++) {
            #pragma unroll
            for (int r = 0; r < 4; r++) {
                const int gr = bm + (w << 5) + (rs << 4) + (quad << 2) + r;
                const int gj = bn + (tl << 4) + m16;
                outF[(size_t)gr * C_ + gj] = acc[rs][tl][r];
            }
        }
    }
}

// ---------------------------------------------------------------------------
extern "C" void kernel_launch(void* const* d_in, const int* in_sizes, int n_in,
                              void* d_out, int out_size, void* d_ws, size_t ws_size,
                              hipStream_t stream) {
    const float* q  = (const float*)d_in[0];
    const float* k  = (const float*)d_in[1];
    const float* v  = (const float*)d_in[2];
    const float* supp_valid = (const float*)d_in[3];
    const int*   supp_mask  = (const int*)d_in[4];
    const float* Wq = (const float*)d_in[5];
    const float* Wk = (const float*)d_in[6];
    const float* Wv = (const float*)d_in[7];
    const float* Wp = (const float*)d_in[8];
    float* out = (float*)d_out;

    char* p = (char*)d_ws;
    _Float16* qhi = (_Float16*)p;      p += 4194304;   // [bh][n][d]
    _Float16* khi = (_Float16*)p;      p += 4194304;
    _Float16* vT  = (_Float16*)p;      p += 4194304;   // [bh] chunk-tiled (k')
    float* xp     = (float*)p;                         // [4][4096][512] f32 (32MB)
    _Float16* qlo = (_Float16*)p;      p += 4194304;   // aliased under xp (dead
    _Float16* klo = (_Float16*)p;      p += 4194304;   //  after argmax)
    p += 25165824;                                     // rest of xp
    _Float16* wH  = (_Float16*)p;      p += 2097152;   // [4][512*512]
    _Float16* wL  = (_Float16*)p;      p += 2097152;
    unsigned long long* q2kP = (unsigned long long*)p; p += 262144;
    unsigned long long* k2qP = (unsigned long long*)p; p += 262144;
    float* lp = (float*)p;             p += 524288;    // [4][16][2048]

    dim3 bG(256);
    wsplit4<<<dim3(256, 4), bG, 0, stream>>>(Wq, Wk, Wv, Wp, wH, wL);
    proj_gemm<<<dim3(32, 8, 3), bG, 0, stream>>>(q, k, v, wH, wL,
                                                 qhi, qlo, khi, klo, vT, q2kP);

    argmax_mfma<<<1024, bG, 0, stream>>>(qhi, qlo, khi, klo, q2kP, k2qP);

    attn_pv<<<1024, bG, 0, stream>>>(qhi, khi, vT, q2kP, k2qP,
                                     supp_mask, supp_valid, xp, lp);

    out_gemm<<<dim3(32, 8), bG, 0, stream>>>(xp, lp,
                                             wH + 3 * 262144, wL + 3 * 262144, out);
}

// Round 10
// 223.130 us; speedup vs baseline: 1.2438x; 1.0064x over previous
//
#include <hip/hip_runtime.h>
#include <hip/hip_bf16.h>
#include <stdint.h>

#define H_ 8
#define NS_ 2048
#define C_ 512
#define HD_ 64
#define SCALE_ 0.125f
#define NEG_ -10000.0f
#define LOG2E_ 1.4426950408889634f
#define MFIX_ 4.0f

typedef _Float16 f16x8_t __attribute__((ext_vector_type(8)));
typedef _Float16 f16x4_t __attribute__((ext_vector_type(4)));
typedef float f32x4_t __attribute__((ext_vector_type(4)));

#define MFMAH(a, b, c) __builtin_amdgcn_mfma_f32_16x16x32_f16(a, b, c, 0, 0, 0)

__device__ inline f16x8_t load_h8(const _Float16* p) {
    return *reinterpret_cast<const f16x8_t*>(p);
}

// async global->LDS, 16B per lane; LDS dest = uniform base + lane*16
__device__ inline void gload_lds16(const void* g, void* l) {
    __builtin_amdgcn_global_load_lds(
        (const __attribute__((address_space(1))) unsigned int*)g,
        (__attribute__((address_space(3))) unsigned int*)l, 16, 0, 0);
}

__device__ inline unsigned orderF(float v) {
    unsigned u = __float_as_uint(v);
    return (u & 0x80000000u) ? ~u : (u | 0x80000000u);
}
__device__ inline unsigned long long packVR(float v, int idx) {
    return ((unsigned long long)orderF(v) << 32) | (unsigned)(~idx);
}
__device__ inline unsigned long long max64(unsigned long long a, unsigned long long b) {
    return a > b ? a : b;
}
__device__ inline unsigned long long shflx64(unsigned long long x, int m) {
    unsigned lo = (unsigned)x, hi = (unsigned)(x >> 32);
    lo = __shfl_xor(lo, m, 64);
    hi = __shfl_xor(hi, m, 64);
    return ((unsigned long long)hi << 32) | lo;
}

// ---------------------------------------------------------------------------
// K0: all four 512x512 weights -> f16 hi/lo splits in one launch.
// ---------------------------------------------------------------------------
__global__ __launch_bounds__(256) void wsplit4(
        const float* __restrict__ w0, const float* __restrict__ w1,
        const float* __restrict__ w2, const float* __restrict__ w3,
        _Float16* __restrict__ hi, _Float16* __restrict__ lo)
{
    const int i = blockIdx.x * 256 + threadIdx.x;            // 65536 float4 / W
    const int y = blockIdx.y;
    const float* src = (y == 0) ? w0 : (y == 1) ? w1 : (y == 2) ? w2 : w3;
    const float4 v = reinterpret_cast<const float4*>(src)[i];
    f16x4_t hv, lv;
    hv[0] = (_Float16)v.x; hv[1] = (_Float16)v.y;
    hv[2] = (_Float16)v.z; hv[3] = (_Float16)v.w;
    lv[0] = (_Float16)(v.x - (float)hv[0]);
    lv[1] = (_Float16)(v.y - (float)hv[1]);
    lv[2] = (_Float16)(v.z - (float)hv[2]);
    lv[3] = (_Float16)(v.w - (float)hv[3]);
    const size_t o = ((size_t)y << 16) + i;                  // float4 index
    reinterpret_cast<f16x4_t*>(hi)[o] = hv;
    reinterpret_cast<f16x4_t*>(lo)[o] = lv;
}

// ---------------------------------------------------------------------------
// K1: projection GEMM (q/k/v via grid.z). 3-term split-f16 MFMA (~fp32) for
// Q/K; V uses hh only (f16 accuracy suffices for the PV path).
// Prologue (z==0 blocks) zero-inits the argmax rowP/colP buffers.
// z<2: hi/lo out [bh][n][d] via LDS-transpose epilogue (b128 stores);
// z==2: V tiled [bh][key>>5][d][k'] with k'=((key&15)<<1)|((key>>4)&1).
// ---------------------------------------------------------------------------
__global__ __launch_bounds__(256) void proj_gemm(
        const float* __restrict__ qin, const float* __restrict__ kin,
        const float* __restrict__ vin,
        const _Float16* __restrict__ wHall, const _Float16* __restrict__ wLall,
        _Float16* __restrict__ qhi, _Float16* __restrict__ qlo,
        _Float16* __restrict__ khi, _Float16* __restrict__ klo,
        _Float16* __restrict__ vT, unsigned long long* __restrict__ pinit)
{
    __shared__ __attribute__((aligned(16))) _Float16 Wsh[2][2][4096];  // 32 KB
    const int zz = blockIdx.z;
    if (zz == 0) {   // zero rowP+colP (65536 u64 over 256 blocks)
        const int bid = (blockIdx.x << 3) + blockIdx.y;
        pinit[(bid << 8) + threadIdx.x] = 0ull;
    }
    const float* A32 = (zz == 0) ? qin : (zz == 1) ? kin : vin;
    const _Float16* Wh = wHall + ((size_t)zz << 18);
    const _Float16* Wl = wLall + ((size_t)zz << 18);
    const int t = threadIdx.x, w = t >> 6, lane = t & 63;
    const int m16 = lane & 15, quad = lane >> 4;
    const int bm = blockIdx.x << 7, bn = blockIdx.y << 6;
    const int r0 = bm + (w << 5) + m16, r1 = r0 + 16;
    const int krow = lane >> 3, kblk = (lane & 7) ^ (krow & 7);
    const int e = m16 & 7;
    const int s00 = (quad ^ e) << 3, s01 = ((4 + quad) ^ e) << 3;
    const f32x4_t z = {0.f, 0.f, 0.f, 0.f};
    f32x4_t acc[2][4];
    #pragma unroll
    for (int rs = 0; rs < 2; rs++)
        #pragma unroll
        for (int tl = 0; tl < 4; tl++) acc[rs][tl] = z;

    auto stageW = [&](int buf, int kc) {
        #pragma unroll
        for (int ci = 0; ci < 4; ci++) {
            const int pp = (w << 2) + ci;
            const int s = pp >> 3, pj = pp & 7;
            if (s && zz == 2) continue;               // V: no lo-W staging
            const _Float16* src = (s ? Wl : Wh)
                + (size_t)(bn + (pj << 3) + krow) * C_ + kc + (kblk << 3);
            gload_lds16(src, &Wsh[buf][s][pj << 9]);
        }
    };
    auto loadA = [&](int kc, f16x8_t* d) {
        #pragma unroll
        for (int rs = 0; rs < 2; rs++) {
            const float* pr = A32 + (size_t)(rs ? r1 : r0) * C_ + kc + (quad << 3);
            #pragma unroll
            for (int seg = 0; seg < 2; seg++) {
                f16x8_t hv, lv;
                #pragma unroll
                for (int i = 0; i < 8; i++) {
                    const float x = pr[seg * 32 + i];
                    const _Float16 hh = (_Float16)x;
                    hv[i] = hh;
                    lv[i] = (zz == 2) ? hh : (_Float16)(x - (float)hh);
                }
                d[rs * 4 + seg] = hv;
                d[rs * 4 + seg + 2] = lv;
            }
        }
    };

    f16x8_t cA[8], nA[8];
    stageW(0, 0);
    loadA(0, cA);
    for (int ch = 0; ch < 8; ch++) {
        __syncthreads();
        if (ch + 1 < 8) {
            stageW((ch + 1) & 1, (ch + 1) << 6);
            loadA((ch + 1) << 6, nA);
        }
        const _Float16* W0 = Wsh[ch & 1][0];
        const _Float16* W1 = Wsh[ch & 1][1];
        #pragma unroll
        for (int tl = 0; tl < 4; tl++) {
            const int j64 = ((tl << 4) + m16) << 6;
            const f16x8_t bh0 = load_h8(&W0[j64 + s00]);
            const f16x8_t bh1 = load_h8(&W0[j64 + s01]);
            f32x4_t c0 = acc[0][tl];
            c0 = MFMAH(cA[0], bh0, c0); c0 = MFMAH(cA[1], bh1, c0);
            f32x4_t c1 = acc[1][tl];
            c1 = MFMAH(cA[4], bh0, c1); c1 = MFMAH(cA[5], bh1, c1);
            if (zz != 2) {                            // Q/K: lo terms for ~fp32
                const f16x8_t bl0 = load_h8(&W1[j64 + s00]);
                const f16x8_t bl1 = load_h8(&W1[j64 + s01]);
                c0 = MFMAH(cA[2], bh0, c0); c0 = MFMAH(cA[3], bh1, c0);
                c0 = MFMAH(cA[0], bl0, c0); c0 = MFMAH(cA[1], bl1, c0);
                c1 = MFMAH(cA[6], bh0, c1); c1 = MFMAH(cA[7], bh1, c1);
                c1 = MFMAH(cA[4], bl0, c1); c1 = MFMAH(cA[5], bl1, c1);
            }
            acc[0][tl] = c0;
            acc[1][tl] = c1;
        }
        #pragma unroll
        for (int i = 0; i < 8; i++) cA[i] = nA[i];
    }
    const int by = blockIdx.y;
    if (zz == 2) {
        #pragma unroll
        for (int rs = 0; rs < 2; rs++) {
            #pragma unroll
            for (int tl = 0; tl < 4; tl++) {
                #pragma unroll
                for (int r = 0; r < 4; r++) {
                    const int gr = bm + (w << 5) + (rs << 4) + (quad << 2) + r;
                    const int b = gr >> 11, n = gr & 2047;
                    const int d = (tl << 4) + m16;
                    const int bh = (b << 3) + by;
                    const int kp = ((n & 15) << 1) | ((n >> 4) & 1);
                    vT[(((size_t)((bh << 6) + (n >> 5)) << 6) + d) * 32 + kp] =
                        (_Float16)acc[rs][tl][r];
                }
            }
        }
    } else {
        // LDS-transpose epilogue: pack (hi,lo) u32 per element; rows are
        // wave-private so only a threadfence separates write/read phases.
        __syncthreads();                               // Wsh reads all done
        unsigned* Tsh = reinterpret_cast<unsigned*>(&Wsh[0][0][0]);  // 8192 u32
        _Float16* o1 = (zz == 0) ? qhi : khi;
        _Float16* o2 = (zz == 0) ? qlo : klo;
        #pragma unroll
        for (int rs = 0; rs < 2; rs++) {
            #pragma unroll
            for (int tl = 0; tl < 4; tl++) {
                #pragma unroll
                for (int r = 0; r < 4; r++) {
                    const int rloc = (w << 5) + (rs << 4) + (quad << 2) + r;
                    const float val = acc[rs][tl][r];
                    union { _Float16 hh[2]; unsigned u; } pk;
                    pk.hh[0] = (_Float16)val;
                    pk.hh[1] = (_Float16)(val - (float)pk.hh[0]);
                    Tsh[(rloc << 6) + (tl << 4) + m16] = pk.u;
                }
            }
        }
        __threadfence_block();
        const int rloc = (w << 5) + (lane >> 1);
        const int gr = bm + rloc;
        const int b = gr >> 11, n = gr & 2047;
        const int bh = (b << 3) + by;
        const size_t obase = ((((size_t)bh << 11) + n) << 6) + ((lane & 1) << 5);
        const unsigned* src = &Tsh[(rloc << 6) + ((lane & 1) << 5)];
        #pragma unroll
        for (int j = 0; j < 4; j++) {
            const uint4 t0 = *reinterpret_cast<const uint4*>(src + (j << 3));
            const uint4 t1 = *reinterpret_cast<const uint4*>(src + (j << 3) + 4);
            uint4 hi4, lo4;
            hi4.x = (t0.x & 0xffffu) | (t0.y << 16);
            hi4.y = (t0.z & 0xffffu) | (t0.w << 16);
            hi4.z = (t1.x & 0xffffu) | (t1.y << 16);
            hi4.w = (t1.z & 0xffffu) | (t1.w << 16);
            lo4.x = (t0.x >> 16) | (t0.y & 0xffff0000u);
            lo4.y = (t0.z >> 16) | (t0.w & 0xffff0000u);
            lo4.z = (t1.x >> 16) | (t1.y & 0xffff0000u);
            lo4.w = (t1.z >> 16) | (t1.w & 0xffff0000u);
            *reinterpret_cast<uint4*>(o1 + obase + (j << 3)) = hi4;
            *reinterpret_cast<uint4*>(o2 + obase + (j << 3)) = lo4;
        }
    }
}

// ---------------------------------------------------------------------------
// K2: MFMA split-f16 argmax. 32 rows/wave, 64-key chunks, dbuf LDS staging,
// key-space split x4 (4 blocks/CU). Row argmax -> global atomicMax; col
// argmax -> in-lane reduce, quad butterfly, LDS atomicMax, block merge.
// XCD-pinned: bh pair {2x,2x+1} on XCD x.  [B-frags from LDS]
// ---------------------------------------------------------------------------
__global__ __launch_bounds__(256) void argmax_mfma(
        const _Float16* __restrict__ qhi, const _Float16* __restrict__ qlo,
        const _Float16* __restrict__ khi, const _Float16* __restrict__ klo,
        unsigned long long* __restrict__ rowP, unsigned long long* __restrict__ colP)
{
    __shared__ __attribute__((aligned(16))) _Float16 Ksh[2][2][4096];  // 32 KB
    __shared__ unsigned long long colbest[512];                        // 4 KB
    const int bx = blockIdx.x;
    const int bh = ((bx & 7) << 1) | (bx >> 9);
    const int mid = (bx >> 3) & 63;
    const int rt = mid & 15, ks = mid >> 4;
    const int t = threadIdx.x, w = t >> 6, lane = t & 63;
    const int m16 = lane & 15, quad = lane >> 4;
    const int wrow = (rt << 7) + (w << 5);
    const size_t qoff0 = ((((size_t)bh << 11) + wrow + m16) << 6) + (quad << 3);
    const size_t qoff1 = qoff0 + 1024;
    const f16x8_t a00h = load_h8(qhi + qoff0), a01h = load_h8(qhi + qoff0 + 32);
    const f16x8_t a00l = load_h8(qlo + qoff0), a01l = load_h8(qlo + qoff0 + 32);
    const f16x8_t a10h = load_h8(qhi + qoff1), a11h = load_h8(qhi + qoff1 + 32);
    const f16x8_t a10l = load_h8(qlo + qoff1), a11l = load_h8(qlo + qoff1 + 32);
    for (int c = t; c < 512; c += 256) colbest[c] = 0;
    const int krow = lane >> 3, kblk = (lane & 7) ^ (krow & 7);
    const int e = m16 & 7;
    const int s00 = (quad ^ e) << 3, s01 = ((4 + quad) ^ e) << 3;
    const size_t kbase = (((size_t)bh << 11) + (ks << 9)) << 6;
    float bv0[4] = {-3.4e38f, -3.4e38f, -3.4e38f, -3.4e38f};
    float bv1[4] = {-3.4e38f, -3.4e38f, -3.4e38f, -3.4e38f};
    int bc0[4] = {0, 0, 0, 0}, bc1[4] = {0, 0, 0, 0};
    const f32x4_t z = {0.f, 0.f, 0.f, 0.f};

    auto stage = [&](int buf, int cidx) {
        const size_t ce = kbase + ((size_t)cidx << 12);
        #pragma unroll
        for (int ci = 0; ci < 4; ci++) {
            const int pp = (w << 2) + ci;
            const int s = pp >> 3, pj = pp & 7;
            const _Float16* src = (s ? klo : khi) + ce + (((pj << 3) + krow) << 6) + (kblk << 3);
            gload_lds16(src, &Ksh[buf][s][pj << 9]);
        }
    };

    stage(0, 0);
    for (int ch = 0; ch < 8; ch++) {
        __syncthreads();
        if (ch + 1 < 8) stage((ch + 1) & 1, ch + 1);
        const _Float16* K0 = Ksh[ch & 1][0];
        const _Float16* K1 = Ksh[ch & 1][1];
        const int kc0 = (ks << 9) + (ch << 6);
        #pragma unroll
        for (int tl = 0; tl < 4; tl++) {
            const int j64 = ((tl << 4) + m16) << 6;
            const f16x8_t bh0 = load_h8(&K0[j64 + s00]);
            const f16x8_t bh1 = load_h8(&K0[j64 + s01]);
            const f16x8_t bl0 = load_h8(&K1[j64 + s00]);
            const f16x8_t bl1 = load_h8(&K1[j64 + s01]);
            f32x4_t c0 = MFMAH(a00h, bh0, z);
            c0 = MFMAH(a01h, bh1, c0);
            c0 = MFMAH(a00l, bh0, c0); c0 = MFMAH(a01l, bh1, c0);
            c0 = MFMAH(a00h, bl0, c0); c0 = MFMAH(a01h, bl1, c0);
            f32x4_t c1 = MFMAH(a10h, bh0, z);
            c1 = MFMAH(a11h, bh1, c1);
            c1 = MFMAH(a10l, bh0, c1); c1 = MFMAH(a11l, bh1, c1);
            c1 = MFMAH(a10h, bl0, c1); c1 = MFMAH(a11h, bl1, c1);
            const int gc = kc0 + (tl << 4) + m16;
            #pragma unroll
            for (int r = 0; r < 4; r++) {
                if (c0[r] > bv0[r]) { bv0[r] = c0[r]; bc0[r] = gc; }
                if (c1[r] > bv1[r]) { bv1[r] = c1[r]; bc1[r] = gc; }
            }
            // col argmax: in-lane over 8 rows (rowset0 first -> smallest row)
            float v = c0[0]; int ri = (quad << 2);
            if (c0[1] > v) { v = c0[1]; ri = (quad << 2) + 1; }
            if (c0[2] > v) { v = c0[2]; ri = (quad << 2) + 2; }
            if (c0[3] > v) { v = c0[3]; ri = (quad << 2) + 3; }
            if (c1[0] > v) { v = c1[0]; ri = 16 + (quad << 2); }
            if (c1[1] > v) { v = c1[1]; ri = 16 + (quad << 2) + 1; }
            if (c1[2] > v) { v = c1[2]; ri = 16 + (quad << 2) + 2; }
            if (c1[3] > v) { v = c1[3]; ri = 16 + (quad << 2) + 3; }
            unsigned long long pk = packVR(v, wrow + ri);
            pk = max64(pk, shflx64(pk, 16));
            pk = max64(pk, shflx64(pk, 32));
            if (quad == 0) atomicMax(&colbest[(ch << 6) + (tl << 4) + m16], pk);
        }
    }
    #pragma unroll
    for (int r = 0; r < 4; r++) {
        unsigned long long p0 = packVR(bv0[r], bc0[r]);
        p0 = max64(p0, shflx64(p0, 1)); p0 = max64(p0, shflx64(p0, 2));
        p0 = max64(p0, shflx64(p0, 4)); p0 = max64(p0, shflx64(p0, 8));
        if (m16 == 0)
            atomicMax(rowP + ((size_t)bh << 11) + wrow + (quad << 2) + r, p0);
        unsigned long long p1 = packVR(bv1[r], bc1[r]);
        p1 = max64(p1, shflx64(p1, 1)); p1 = max64(p1, shflx64(p1, 2));
        p1 = max64(p1, shflx64(p1, 4)); p1 = max64(p1, shflx64(p1, 8));
        if (m16 == 0)
            atomicMax(rowP + ((size_t)bh << 11) + wrow + 16 + (quad << 2) + r, p1);
    }
    __syncthreads();
    for (int c = t; c < 512; c += 256)
        atomicMax(colP + ((size_t)bh << 11) + (ks << 9) + c, colbest[c]);
}

// ---------------------------------------------------------------------------
// K4: fused attention (resolve folded into prologue). 32 rows/wave, LDS-
// staged K/V (dbuf, XOR swizzle), key-split x4 (1024 blocks, 4/CU).
// p = exp2(s+vn) (fixed max); P packed (p0,p1) u32 -> stride-20 wave strips
// (k'-interleaved, matching vT); l via ones-MFMA; partial x/l per ks.
// ---------------------------------------------------------------------------
__global__ __launch_bounds__(256, 4) void attn_pv(
        const _Float16* __restrict__ qh, const _Float16* __restrict__ kh,
        const _Float16* __restrict__ vT,
        const unsigned long long* __restrict__ q2kP,
        const unsigned long long* __restrict__ k2qP,
        const int* __restrict__ supp_mask, const float* __restrict__ supp_valid,
        float* __restrict__ xp, float* __restrict__ lp)
{
    __shared__ __attribute__((aligned(16))) _Float16 Ksh[2][2048];    // 8 KB
    __shared__ __attribute__((aligned(16))) _Float16 Vsh[2][2048];    // 8 KB
    __shared__ float vnL[512];                                        // 2 KB
    __shared__ __attribute__((aligned(16))) unsigned pbuf[4][2][320]; // 10 KB
    const int bx = blockIdx.x;
    const int bh = ((bx & 7) << 1) | (bx >> 9);
    const int mid = (bx >> 3) & 63;
    const int rt = mid & 15, ks = mid >> 4;
    const int t = threadIdx.x, w = t >> 6, lane = t & 63;
    const int m16 = lane & 15, quad = lane >> 4;
    const int b = bh >> 3, h = bh & 7;
    // --- fused resolve for this block's 512-key slice ---
    for (int c = t; c < 512; c += 256) {
        const int j = (ks << 9) + c;
        const unsigned k2q = ~(unsigned)(k2qP[(bh << 11) + j] & 0xFFFFFFFFull);
        const unsigned rm  = ~(unsigned)(q2kP[(bh << 11) + k2q] & 0xFFFFFFFFull);
        const int asso = supp_mask[(b << 11) + j] == supp_mask[(b << 11) + (int)rm];
        const float valid = asso ? supp_valid[(b << 11) + j] : 1.0f;
        vnL[c] = fmaf(valid, NEG_ * LOG2E_, -MFIX_);
    }
    const int rowbase = (rt << 7) + (w << 5);
    const size_t qoff = ((((size_t)bh << 11) + rowbase + m16) << 6) + (quad << 3);
    const f16x8_t a0 = load_h8(qh + qoff),        a1 = load_h8(qh + qoff + 32);
    const f16x8_t a2 = load_h8(qh + qoff + 1024), a3 = load_h8(qh + qoff + 1056);
    const float KS = SCALE_ * LOG2E_;
    const int krow = lane >> 3, kblk = (lane & 7) ^ ((lane >> 3) & 7);
    const int vrow = lane >> 2, vblk = (lane & 3) ^ ((lane >> 3) & 3);
    const int e = m16 & 7;
    const int s00 = (quad ^ e) << 3, s01 = ((4 + quad) ^ e) << 3;
    const int vsw = (m16 >> 1) & 3;
    f16x8_t ones;
    #pragma unroll
    for (int i = 0; i < 8; i++) ones[i] = (_Float16)1.0f;
    const f32x4_t z = {0.f, 0.f, 0.f, 0.f};
    f32x4_t xa0[4], xa1[4], la0 = z, la1 = z;
    #pragma unroll
    for (int nt = 0; nt < 4; nt++) { xa0[nt] = z; xa1[nt] = z; }
    const size_t kbel = ((size_t)bh << 11) * HD_;
    unsigned* pw0 = pbuf[w][0];
    unsigned* pw1 = pbuf[w][1];

    auto stage = [&](int buf, int ch) {
        const int kcg = (ks << 9) + (ch << 5);
        const size_t ce = kbel + (size_t)kcg * HD_;
        const size_t ve = ((size_t)(bh << 6) + (kcg >> 5)) << 11;
        #pragma unroll
        for (int ci = 0; ci < 2; ci++) {
            const int call = (w << 1) + ci;
            if (call < 4) {
                const _Float16* src = kh + ce + ((call * 8 + krow) << 6) + (kblk << 3);
                gload_lds16(src, &Ksh[buf][call << 9]);
            } else {
                const int j = call - 4;
                const _Float16* src = vT + ve + ((j * 16 + vrow) << 5) + (vblk << 3);
                gload_lds16(src, &Vsh[buf][j << 9]);
            }
        }
    };

    stage(0, 0);
    for (int ch = 0; ch < 16; ch++) {
        __syncthreads();
        if (ch + 1 < 16) stage((ch + 1) & 1, ch + 1);
        const _Float16* K = Ksh[ch & 1];
        const _Float16* V = Vsh[ch & 1];
        const f16x8_t b00 = load_h8(&K[(m16 << 6) + s00]);
        const f16x8_t b01 = load_h8(&K[(m16 << 6) + s01]);
        const f16x8_t b10 = load_h8(&K[((16 + m16) << 6) + s00]);
        const f16x8_t b11 = load_h8(&K[((16 + m16) << 6) + s01]);
        f32x4_t c0 = MFMAH(a0, b00, z); c0 = MFMAH(a1, b01, c0);
        f32x4_t c1 = MFMAH(a0, b10, z); c1 = MFMAH(a1, b11, c1);
        f32x4_t c2 = MFMAH(a2, b00, z); c2 = MFMAH(a3, b01, c2);
        f32x4_t c3 = MFMAH(a2, b10, z); c3 = MFMAH(a3, b11, c3);
        const float vn0 = vnL[(ch << 5) + m16], vn1 = vnL[(ch << 5) + 16 + m16];
        #pragma unroll
        for (int r = 0; r < 4; r++) {
            union { _Float16 hh[2]; unsigned u; } pk0, pk1;
            pk0.hh[0] = (_Float16)exp2f(fmaf(c0[r], KS, vn0));  // key kc+m16    -> k'=2*m16
            pk0.hh[1] = (_Float16)exp2f(fmaf(c1[r], KS, vn1));  // key kc+16+m16 -> k'=2*m16+1
            pw0[((quad << 2) + r) * 20 + m16] = pk0.u;
            pk1.hh[0] = (_Float16)exp2f(fmaf(c2[r], KS, vn0));
            pk1.hh[1] = (_Float16)exp2f(fmaf(c3[r], KS, vn1));
            pw1[((quad << 2) + r) * 20 + m16] = pk1.u;
        }
        __threadfence_block();   // order P writes before same-wave P reads
        const f16x8_t pa0 = *reinterpret_cast<const f16x8_t*>(&pw0[m16 * 20 + (quad << 2)]);
        const f16x8_t pa1 = *reinterpret_cast<const f16x8_t*>(&pw1[m16 * 20 + (quad << 2)]);
        la0 = MFMAH(pa0, ones, la0);
        la1 = MFMAH(pa1, ones, la1);
        #pragma unroll
        for (int nt = 0; nt < 4; nt++) {
            const f16x8_t vb = load_h8(&V[((nt * 16 + m16) << 5) + ((quad ^ vsw) << 3)]);
            xa0[nt] = MFMAH(pa0, vb, xa0[nt]);
            xa1[nt] = MFMAH(pa1, vb, xa1[nt]);
        }
    }
    if (m16 == 0) {
        #pragma unroll
        for (int r = 0; r < 4; r++) {
            lp[((size_t)ks << 15) + (bh << 11) + rowbase + (quad << 2) + r] = la0[r];
            lp[((size_t)ks << 15) + (bh << 11) + rowbase + 16 + (quad << 2) + r] = la1[r];
        }
    }
    const size_t xbase = ((size_t)ks << 21);
    #pragma unroll
    for (int r = 0; r < 4; r++) {
        const int row0 = rowbase + (quad << 2) + r;
        #pragma unroll
        for (int nt = 0; nt < 4; nt++) {
            xp[xbase + (((size_t)(b << 11) + row0) << 9) + (h << 6) + (nt << 4) + m16] = xa0[nt][r];
            xp[xbase + (((size_t)(b << 11) + row0 + 16) << 9) + (h << 6) + (nt << 4) + m16] = xa1[nt][r];
        }
    }
}

// ---------------------------------------------------------------------------
// K5: output GEMM. A = (sum of 4 xp partials) * (1/sum of 4 l partials),
// split to f16 hi/lo on the fly; out[m,j] = sum_k A[m,k]*Wproj[j,k].
// ---------------------------------------------------------------------------
__global__ __launch_bounds__(256) void out_gemm(
        const float* __restrict__ xp, const float* __restrict__ lp,
        const _Float16* __restrict__ Wh, const _Float16* __restrict__ Wl,
        float* __restrict__ outF)
{
    __shared__ __attribute__((aligned(16))) _Float16 Wsh[2][2][4096];  // 32 KB
    const int t = threadIdx.x, w = t >> 6, lane = t & 63;
    const int m16 = lane & 15, quad = lane >> 4;
    const int bm = blockIdx.x << 7, bn = blockIdx.y << 6;
    const int r0 = bm + (w << 5) + m16, r1 = r0 + 16;
    const int krow = lane >> 3, kblk = (lane & 7) ^ (krow & 7);
    const int e = m16 & 7;
    const int s00 = (quad ^ e) << 3, s01 = ((4 + quad) ^ e) << 3;
    const f32x4_t z = {0.f, 0.f, 0.f, 0.f};
    f32x4_t acc[2][4];
    #pragma unroll
    for (int rs = 0; rs < 2; rs++)
        #pragma unroll
        for (int tl = 0; tl < 4; tl++) acc[rs][tl] = z;

    auto stageW = [&](int buf, int kc) {
        #pragma unroll
        for (int ci = 0; ci < 4; ci++) {
            const int pp = (w << 2) + ci;
            const int s = pp >> 3, pj = pp & 7;
            const _Float16* src = (s ? Wl : Wh)
                + (size_t)(bn + (pj << 3) + krow) * C_ + kc + (kblk << 3);
            gload_lds16(src, &Wsh[buf][s][pj << 9]);
        }
    };
    auto loadA = [&](int ch, f16x8_t* d) {
        const int kc = ch << 6;                       // head = ch
        #pragma unroll
        for (int rs = 0; rs < 2; rs++) {
            const int r = rs ? r1 : r0;
            const int b = r >> 11, n = r & 2047;
            const size_t li = ((size_t)((b << 3) + ch) << 11) + n;
            const float linv = 1.0f / (lp[li] + lp[32768 + li] + lp[65536 + li] + lp[98304 + li]);
            const size_t base = ((size_t)r << 9) + kc + (quad << 3);
            #pragma unroll
            for (int seg = 0; seg < 2; seg++) {
                f16x8_t hv, lv;
                #pragma unroll
                for (int i = 0; i < 8; i++) {
                    const size_t o = base + seg * 32 + i;
                    const float x = (xp[o] + xp[2097152 + o] + xp[4194304 + o] + xp[6291456 + o]) * linv;
                    const _Float16 hh = (_Float16)x;
                    hv[i] = hh;
                    lv[i] = (_Float16)(x - (float)hh);
                }
                d[rs * 4 + seg] = hv;
                d[rs * 4 + seg + 2] = lv;
            }
        }
    };

    f16x8_t cA[8], nA[8];
    stageW(0, 0);
    loadA(0, cA);
    for (int ch = 0; ch < 8; ch++) {
        __syncthreads();
        if (ch + 1 < 8) {
            stageW((ch + 1) & 1, (ch + 1) << 6);
            loadA(ch + 1, nA);
        }
        const _Float16* W0 = Wsh[ch & 1][0];
        const _Float16* W1 = Wsh[ch & 1][1];
        #pragma unroll
        for (int tl = 0; tl < 4; tl++) {
            const int j64 = ((tl << 4) + m16) << 6;
            const f16x8_t bh0 = load_h8(&W0[j64 + s00]);
            const f16x8_t bh1 = load_h8(&W0[j64 + s01]);
            const f16x8_t bl0 = load_h8(&W1[j64 + s00]);
            const f16x8_t bl1 = load_h8(&W1[j64 + s01]);
            f32x4_t c0 = acc[0][tl];
            c0 = MFMAH(cA[0], bh0, c0); c0 = MFMAH(cA[1], bh1, c0);
            c0 = MFMAH(cA[2], bh0, c0); c0 = MFMAH(cA[3], bh1, c0);
            c0 = MFMAH(cA[0], bl0, c0); c0 = MFMAH(cA[1], bl1, c0);
            acc[0][tl] = c0;
            f32x4_t c1 = acc[1][tl];
            c1 = MFMAH(cA[4], bh0, c1); c1 = MFMAH(cA[5], bh1, c1);
            c1 = MFMAH(cA[6], bh0, c1); c1 = MFMAH(cA[7], bh1, c1);
            c1 = MFMAH(cA[4], bl0, c1); c1 = MFMAH(cA[5], bl1, c1);
            acc[1][tl] = c1;
        }
        #pragma unroll
        for (int i = 0; i < 8; i++) cA[i] = nA[i];
    }
    #pragma unroll
    for (int rs = 0; rs < 2; rs++) {
        #pragma unroll
        for (int tl = 0; tl < 4; tl++) {
            #pragma unroll
            for (int r = 0; r < 4; r++) {
                const int gr = bm + (w << 5) + (rs << 4) + (quad << 2) + r;
                const int gj = bn + (tl << 4) + m16;
                outF[(size_t)gr * C_ + gj] = acc[rs][tl][r];
            }
        }
    }
}

// ---------------------------------------------------------------------------
extern "C" void kernel_launch(void* const* d_in, const int* in_sizes, int n_in,
                              void* d_out, int out_size, void* d_ws, size_t ws_size,
                              hipStream_t stream) {
    const float* q  = (const float*)d_in[0];
    const float* k  = (const float*)d_in[1];
    const float* v  = (const float*)d_in[2];
    const float* supp_valid = (const float*)d_in[3];
    const int*   supp_mask  = (const int*)d_in[4];
    const float* Wq = (const float*)d_in[5];
    const float* Wk = (const float*)d_in[6];
    const float* Wv = (const float*)d_in[7];
    const float* Wp = (const float*)d_in[8];
    float* out = (float*)d_out;

    char* p = (char*)d_ws;
    _Float16* qhi = (_Float16*)p;      p += 4194304;   // [bh][n][d]
    _Float16* khi = (_Float16*)p;      p += 4194304;
    _Float16* vT  = (_Float16*)p;      p += 4194304;   // [bh] chunk-tiled (k')
    float* xp     = (float*)p;                         // [4][4096][512] f32 (32MB)
    _Float16* qlo = (_Float16*)p;      p += 4194304;   // aliased under xp (dead
    _Float16* klo = (_Float16*)p;      p += 4194304;   //  after argmax)
    p += 25165824;                                     // rest of xp
    _Float16* wH  = (_Float16*)p;      p += 2097152;   // [4][512*512]
    _Float16* wL  = (_Float16*)p;      p += 2097152;
    unsigned long long* q2kP = (unsigned long long*)p; p += 262144;
    unsigned long long* k2qP = (unsigned long long*)p; p += 262144;
    float* lp = (float*)p;             p += 524288;    // [4][16][2048]

    dim3 bG(256);
    wsplit4<<<dim3(256, 4), bG, 0, stream>>>(Wq, Wk, Wv, Wp, wH, wL);
    proj_gemm<<<dim3(32, 8, 3), bG, 0, stream>>>(q, k, v, wH, wL,
                                                 qhi, qlo, khi, klo, vT, q2kP);

    argmax_mfma<<<1024, bG, 0, stream>>>(qhi, qlo, khi, klo, q2kP, k2qP);

    attn_pv<<<1024, bG, 0, stream>>>(qhi, khi, vT, q2kP, k2qP,
                                     supp_mask, supp_valid, xp, lp);

    out_gemm<<<dim3(32, 8), bG, 0, stream>>>(xp, lp,
                                             wH + 3 * 262144, wL + 3 * 262144, out);
}